// Round 7
// baseline (196.068 us; speedup 1.0000x reference)
//
#include <hip/hip_runtime.h>

// out[r,f] = bias[f] + sum_{i: rows[i]==r} value[i] * weight[cols[i], f]
// R15 pipeline (3 kernels): k_init -> k_bin_fixed (fixed-stride bucket slots,
// PADDED cursor: 1 counter / 64B line) -> k_spmm9 (= the measured-60us spmm5
// structure on the fixed-slot layout, + overflow tail).
// History: R9/R11: per-element LDS atomic accumulate = 256M lane RMWs ->
// 1310us, dead end. R14: double-buffered consumer REGRESSED (69 vs 60us:
// halved chunk -> degenerate batching + divergence; rank shares the VALU
// port with consume). R15 post-mortem target: cursorF was 16 counters per
// 64B cache line; ~1M global atomic RMWs serialized ~16K-deep per line at
// L2. Padding to stride-16 ints cuts per-line depth to ~1K.
//
// pair pack (u64): val[63:32] | fine[29:20] | lr[19:13] | col[12:0]

#define NBF 1024
#define DMAX 128     // lr 7 bits => d <= 128 (n <= 131072)
#define CH 4096      // binning chunk
#define CC 1536      // consumer sort chunk
#define SP_T 512
#define CSTR 16      // cursorF stride (ints) = one counter per 64B line

__device__ __forceinline__ void ds_fadd(float* p, float v) {
    unsigned a = (unsigned)(unsigned long long)p;  // LDS byte offset
    asm volatile("ds_add_f32 %0, %1" :: "v"(a), "v"(v) : "memory");
}

__global__ void k_init(int* __restrict__ cursorF, int* __restrict__ ovfCnt, int slots) {
    cursorF[threadIdx.x * CSTR] = threadIdx.x * slots;
    if (threadIdx.x == 0) *ovfCnt = 0;
}

// Single-pass fine bin into fixed-stride bucket slots. Per-chunk LDS hist +
// scan + stage for coalesced writes; one global atomicAdd per (block,bin)
// on a line-padded cursor reserves space; spill to ovf on window overflow
// (statistically never for uniform rows).
__global__ __launch_bounds__(1024) void k_bin_fixed(const int* __restrict__ rows,
        const int* __restrict__ cols, const float* __restrict__ vals, int nnz,
        unsigned M, int S, int d, int slots, int* __restrict__ cursorF,
        unsigned long long* __restrict__ pairs1, int* __restrict__ ovfCnt,
        unsigned long long* __restrict__ ovf) {
    __shared__ unsigned long long stage[CH];
    __shared__ int histF[NBF], scF[NBF], adjF[NBF];
    __shared__ int wsum[16];
    int t = threadIdx.x, lane = t & 63, wv = t >> 6;
    long long base = (long long)blockIdx.x * CH;
    int count = (int)min((long long)CH, (long long)nnz - base);
    histF[t] = 0;
    __syncthreads();
    int f4[4], rk4[4];
    unsigned long long pk4[4];
#pragma unroll
    for (int k = 0; k < 4; ++k) {
        int i = t + (k << 10);
        f4[k] = -1;
        if (i < count) {
            unsigned r = (unsigned)rows[base + i];
            int c = cols[base + i];
            float vv = vals[base + i];
            int f = (int)(((unsigned long long)r * M) >> S);
            int lr = (int)r - f * d;
            f4[k] = f;
            rk4[k] = atomicAdd(&histF[f], 1);
            pk4[k] = ((unsigned long long)__float_as_uint(vv) << 32) |
                     ((unsigned)f << 20) | ((unsigned)lr << 13) | (unsigned)c;
        }
    }
    __syncthreads();
    int v = histF[t], x = v;
#pragma unroll
    for (int off = 1; off < 64; off <<= 1) {
        int y = __shfl_up(x, off, 64);
        if (lane >= off) x += y;
    }
    if (lane == 63) wsum[wv] = x;
    __syncthreads();
    if (t < 16) {
        int s = wsum[t], xs = s;
#pragma unroll
        for (int off = 1; off < 16; off <<= 1) {
            int y = __shfl_up(xs, off, 16);
            if (t >= off) xs += y;
        }
        wsum[t] = xs - s;
    }
    __syncthreads();
    int incl = x + wsum[wv];
    scF[t] = incl;
    if (v > 0) {
        int g = atomicAdd(&cursorF[t * CSTR], v);
        adjF[t] = g - (incl - v);
    }
    __syncthreads();
#pragma unroll
    for (int k = 0; k < 4; ++k)
        if (f4[k] >= 0) stage[(scF[f4[k]] - histF[f4[k]]) + rk4[k]] = pk4[k];
    __syncthreads();
    for (int i = t; i < count; i += 1024) {
        unsigned long long p = stage[i];
        int f = (int)((p >> 20) & 1023);
        int dest = adjF[f] + i;
        if (dest < (f + 1) * slots) pairs1[dest] = p;
        else ovf[atomicAdd(ovfCnt, 1)] = p;
    }
}

// Consumer: spmm5 structure (measured 60-62us) on the fixed-slot layout.
// One block per bucket, 38.4 KB LDS => 4 blocks/CU. Sort chunk by local row
// (int LDS atomics + shfl scan), then 16-lane groups walk whole rows with
// 4-wide batched weight loads. Overflow tail via ds_add_f32 + explicit
// lgkmcnt drain (R11 lesson: inline-asm DS ops are invisible to the
// compiler's waitcnt scoreboard).
__global__ __launch_bounds__(SP_T, 8) void k_spmm9(
        const unsigned long long* __restrict__ pairs, const int* __restrict__ cursorF,
        const int* __restrict__ ovfCnt, const unsigned long long* __restrict__ ovf,
        const float* __restrict__ weight, const float* __restrict__ bias,
        float* __restrict__ out, int d, int n, int slots) {
    __shared__ unsigned long long stage[CC];   // 12 KB
    __shared__ int histR[DMAX], scR[DMAX];     // 1 KB
    extern __shared__ float acc[];             // d*64 floats (25 KB @ d=98)
    int b = blockIdx.x, t = threadIdx.x;
    int row0 = b * d;
    if (row0 >= n) return;
    int nrows = min(d, n - row0);
    long long sbase = (long long)b * slots;
    int cnt = cursorF[b * CSTR] - (int)sbase;
    if (cnt > slots) cnt = slots;
    if (cnt < 0) cnt = 0;

    for (int i = t; i < (nrows << 6); i += SP_T) acc[i] = 0.0f;

    int g = t >> 4, fq = t & 15;
    for (int cb = 0; cb < cnt; cb += CC) {
        int ccnt = min(CC, cnt - cb);
        if (t < DMAX) histR[t] = 0;
        __syncthreads();
        int lr3[3], rk3[3];
        unsigned long long pk3[3];
#pragma unroll
        for (int k = 0; k < 3; ++k) {
            int i = t + (k << 9);
            lr3[k] = -1;
            if (i < ccnt) {
                unsigned long long p = pairs[sbase + cb + i];
                int lr = (int)((p >> 13) & 127);
                lr3[k] = lr;
                rk3[k] = atomicAdd(&histR[lr], 1);
                pk3[k] = p;
            }
        }
        __syncthreads();
        if (t < DMAX) {
            int v = histR[t], x = v;
            int lane = t & 63;
#pragma unroll
            for (int off = 1; off < 64; off <<= 1) {
                int y = __shfl_up(x, off, 64);
                if (lane >= off) x += y;
            }
            scR[t] = x;
        }
        __syncthreads();
        if (t >= 64 && t < DMAX) scR[t] += scR[63];
        __syncthreads();
#pragma unroll
        for (int k = 0; k < 3; ++k)
            if (lr3[k] >= 0) stage[(scR[lr3[k]] - histR[lr3[k]]) + rk3[k]] = pk3[k];
        __syncthreads();

        for (int r = g; r < nrows; r += 32) {
            int e = scR[r], s = e - histR[r];
            if (s >= e) continue;
            float4 a = {0.0f, 0.0f, 0.0f, 0.0f};
            int j = s;
            for (; j + 4 <= e; j += 4) {
                unsigned long long p0 = stage[j + 0];
                unsigned long long p1 = stage[j + 1];
                unsigned long long p2 = stage[j + 2];
                unsigned long long p3 = stage[j + 3];
                const float4 w0 = *(const float4*)(weight + (((int)(p0 & 8191)) << 6) + (fq << 2));
                const float4 w1 = *(const float4*)(weight + (((int)(p1 & 8191)) << 6) + (fq << 2));
                const float4 w2 = *(const float4*)(weight + (((int)(p2 & 8191)) << 6) + (fq << 2));
                const float4 w3 = *(const float4*)(weight + (((int)(p3 & 8191)) << 6) + (fq << 2));
                float v0 = __uint_as_float((unsigned)(p0 >> 32));
                float v1 = __uint_as_float((unsigned)(p1 >> 32));
                float v2 = __uint_as_float((unsigned)(p2 >> 32));
                float v3 = __uint_as_float((unsigned)(p3 >> 32));
                a.x = fmaf(v0, w0.x, a.x); a.y = fmaf(v0, w0.y, a.y);
                a.z = fmaf(v0, w0.z, a.z); a.w = fmaf(v0, w0.w, a.w);
                a.x = fmaf(v1, w1.x, a.x); a.y = fmaf(v1, w1.y, a.y);
                a.z = fmaf(v1, w1.z, a.z); a.w = fmaf(v1, w1.w, a.w);
                a.x = fmaf(v2, w2.x, a.x); a.y = fmaf(v2, w2.y, a.y);
                a.z = fmaf(v2, w2.z, a.z); a.w = fmaf(v2, w2.w, a.w);
                a.x = fmaf(v3, w3.x, a.x); a.y = fmaf(v3, w3.y, a.y);
                a.z = fmaf(v3, w3.z, a.z); a.w = fmaf(v3, w3.w, a.w);
            }
            for (; j < e; ++j) {
                unsigned long long p = stage[j];
                float vv = __uint_as_float((unsigned)(p >> 32));
                const float4 w = *(const float4*)(weight + (((int)(p & 8191)) << 6) + (fq << 2));
                a.x = fmaf(vv, w.x, a.x); a.y = fmaf(vv, w.y, a.y);
                a.z = fmaf(vv, w.z, a.z); a.w = fmaf(vv, w.w, a.w);
            }
            float4* ap = (float4*)&acc[(r << 6) + (fq << 2)];
            float4 o = *ap;
            o.x += a.x; o.y += a.y; o.z += a.z; o.w += a.w;
            *ap = o;
        }
        __syncthreads();
    }

    // overflow (spilled pairs): statistically empty for uniform rows.
    int oc = *ovfCnt;
    if (oc > 0) {
        __syncthreads();
        for (int i = g; i < oc; i += (SP_T >> 4)) {
            unsigned long long p = ovf[i];
            if ((int)((p >> 20) & 1023) == b) {
                int lr = (int)((p >> 13) & 127);
                int cc = (int)(p & 8191);
                float vv = __uint_as_float((unsigned)(p >> 32));
                const float4 w = *(const float4*)(weight + (cc << 6) + (fq << 2));
                float* ap = &acc[(lr << 6) + (fq << 2)];
                ds_fadd(ap + 0, vv * w.x); ds_fadd(ap + 1, vv * w.y);
                ds_fadd(ap + 2, vv * w.z); ds_fadd(ap + 3, vv * w.w);
            }
        }
        asm volatile("s_waitcnt lgkmcnt(0)" ::: "memory");
        __builtin_amdgcn_sched_barrier(0);
        __syncthreads();
    }

    for (int i = t; i < (nrows << 6); i += SP_T)
        out[((long long)row0 << 6) + i] = acc[i] + bias[i & 63];
}

extern "C" void kernel_launch(void* const* d_in, const int* in_sizes, int n_in,
                              void* d_out, int out_size, void* d_ws, size_t ws_size,
                              hipStream_t stream) {
    const int*   index  = (const int*)d_in[0];
    const float* value  = (const float*)d_in[1];
    const float* weight = (const float*)d_in[3];
    const float* bias   = (const float*)d_in[4];
    float*       out    = (float*)d_out;

    int nnz = in_sizes[0] / 2;
    int n   = out_size / 64;
    const int* rows = index;
    const int* cols = index + nnz;

    int d = (n + NBF - 1) / NBF;  // 98 for n=100000 (<= DMAX)
    unsigned M = 0;
    int S = 0;
    for (S = 20; S <= 40; ++S) {
        unsigned long long m = ((1ull << S) + (unsigned)d - 1) / (unsigned)d;
        unsigned long long e = m * (unsigned long long)d - (1ull << S);
        if (m <= 0xffffffffull && e * (unsigned long long)(n > 0 ? n - 1 : 0) < (1ull << S)) {
            M = (unsigned)m;
            break;
        }
    }

    int nChunks = (nnz + CH - 1) / CH;
    char* ws = (char*)d_ws;
    int* cursorF = (int*)ws;                  // 64 KB (1024 counters, 64B stride)
    int* ovfCnt  = (int*)(ws + (64 << 10));
    unsigned long long* pairsS = (unsigned long long*)(ws + (128 << 10));

    size_t szOvf = (((size_t)nnz * 8) + 255) & ~(size_t)255;
    size_t availS = (ws_size > (128 << 10) + szOvf) ? (ws_size - (128 << 10) - szOvf) : 0;
    long long slotsL = (long long)(availS / ((size_t)NBF * 8));
    int slots = (int)(slotsL > 6144 ? 6144 : slotsL);
    if (slots > 64) slots &= ~63;
    if (slots < 1) slots = 1;
    unsigned long long* ovf = (unsigned long long*)(ws + (128 << 10) + (size_t)slots * NBF * 8);

    k_init<<<1, 1024, 0, stream>>>(cursorF, ovfCnt, slots);
    k_bin_fixed<<<nChunks, 1024, 0, stream>>>(rows, cols, value, nnz, M, S, d, slots,
                                              cursorF, pairsS, ovfCnt, ovf);
    size_t smem = (size_t)d * 64 * sizeof(float);
    k_spmm9<<<NBF, SP_T, smem, stream>>>(pairsS, cursorF, ovfCnt, ovf, weight, bias,
                                         out, d, n, slots);
}

// Round 8
// 184.592 us; speedup vs baseline: 1.0622x; 1.0622x over previous
//
#include <hip/hip_runtime.h>

// out[r,f] = bias[f] + sum_{i: rows[i]==r} value[i] * weight[cols[i], f]
// R16 pipeline (3 kernels): k_init -> k_bin_fixed (CH=8192: full-line runs)
// -> k_spmm9 (CC=3072: half the sort phases, 3 blocks/CU).
// History: R9/R11: per-element LDS atomic accumulate -> 1310us, dead end.
// R14: double-buffered consumer regressed (69us). R15: cursor-padding null
// result -> cursor atomics never critical; k_bin_fixed's real problem is
// store fragmentation: CH=4096/1024 bins = 4-pair (32B) runs -> WRITE_SIZE
// 80MB for 32MB payload (2.5x amplification, partial-line RMW). R16: CH=8192
// doubles runs to 64B full lines (2 blocks/CU unchanged — was already
// thread-capped); consumer CC=3072 halves barrier phases, doubles row
// segments (launch_bounds(512,6), 3 blocks/CU matches the 50.7KB LDS).
//
// pair pack (u64): val[63:32] | fine[29:20] | lr[19:13] | col[12:0]

#define NBF 1024
#define DMAX 128     // lr 7 bits => d <= 128 (n <= 131072)
#define CH 8192      // binning chunk (8/thread)
#define CC 3072      // consumer sort chunk (6/thread)
#define SP_T 512
#define CSTR 16      // cursorF stride (ints)

__device__ __forceinline__ void ds_fadd(float* p, float v) {
    unsigned a = (unsigned)(unsigned long long)p;  // LDS byte offset
    asm volatile("ds_add_f32 %0, %1" :: "v"(a), "v"(v) : "memory");
}

__global__ void k_init(int* __restrict__ cursorF, int* __restrict__ ovfCnt, int slots) {
    cursorF[threadIdx.x * CSTR] = threadIdx.x * slots;
    if (threadIdx.x == 0) *ovfCnt = 0;
}

// Single-pass fine bin into fixed-stride bucket slots. Per-chunk LDS hist +
// scan + stage; one global atomicAdd per (block,bin) reserves space; spill
// to ovf on window overflow (statistically never for uniform rows).
__global__ __launch_bounds__(1024) void k_bin_fixed(const int* __restrict__ rows,
        const int* __restrict__ cols, const float* __restrict__ vals, int nnz,
        unsigned M, int S, int d, int slots, int* __restrict__ cursorF,
        unsigned long long* __restrict__ pairs1, int* __restrict__ ovfCnt,
        unsigned long long* __restrict__ ovf) {
    __shared__ unsigned long long stage[CH];       // 64 KB
    __shared__ int histF[NBF], scF[NBF], adjF[NBF];// 12 KB
    __shared__ int wsum[16];
    int t = threadIdx.x, lane = t & 63, wv = t >> 6;
    long long base = (long long)blockIdx.x * CH;
    int count = (int)min((long long)CH, (long long)nnz - base);
    histF[t] = 0;
    __syncthreads();
    int f8[8], rk8[8];
    unsigned long long pk8[8];
#pragma unroll
    for (int k = 0; k < 8; ++k) {
        int i = t + (k << 10);
        f8[k] = -1;
        if (i < count) {
            unsigned r = (unsigned)rows[base + i];
            int c = cols[base + i];
            float vv = vals[base + i];
            int f = (int)(((unsigned long long)r * M) >> S);
            int lr = (int)r - f * d;
            f8[k] = f;
            rk8[k] = atomicAdd(&histF[f], 1);
            pk8[k] = ((unsigned long long)__float_as_uint(vv) << 32) |
                     ((unsigned)f << 20) | ((unsigned)lr << 13) | (unsigned)c;
        }
    }
    __syncthreads();
    int v = histF[t], x = v;
#pragma unroll
    for (int off = 1; off < 64; off <<= 1) {
        int y = __shfl_up(x, off, 64);
        if (lane >= off) x += y;
    }
    if (lane == 63) wsum[wv] = x;
    __syncthreads();
    if (t < 16) {
        int s = wsum[t], xs = s;
#pragma unroll
        for (int off = 1; off < 16; off <<= 1) {
            int y = __shfl_up(xs, off, 16);
            if (t >= off) xs += y;
        }
        wsum[t] = xs - s;
    }
    __syncthreads();
    int incl = x + wsum[wv];
    scF[t] = incl;
    if (v > 0) {
        int g = atomicAdd(&cursorF[t * CSTR], v);
        adjF[t] = g - (incl - v);
    }
    __syncthreads();
#pragma unroll
    for (int k = 0; k < 8; ++k)
        if (f8[k] >= 0) stage[(scF[f8[k]] - histF[f8[k]]) + rk8[k]] = pk8[k];
    __syncthreads();
    for (int i = t; i < count; i += 1024) {
        unsigned long long p = stage[i];
        int f = (int)((p >> 20) & 1023);
        int dest = adjF[f] + i;
        if (dest < (f + 1) * slots) pairs1[dest] = p;
        else ovf[atomicAdd(ovfCnt, 1)] = p;
    }
}

// Consumer: spmm5 structure on fixed-slot layout, CC=3072 (6/thread).
// LDS: stage 24KB + histR/scR 1KB + acc 25KB = 50.7KB -> 3 blocks/CU.
// Sort chunk by local row (int LDS atomics + shfl scan), then 16-lane
// groups walk whole rows with 4-wide batched weight loads. Overflow tail
// via ds_add_f32 + explicit lgkmcnt drain (R11 lesson).
__global__ __launch_bounds__(SP_T, 6) void k_spmm9(
        const unsigned long long* __restrict__ pairs, const int* __restrict__ cursorF,
        const int* __restrict__ ovfCnt, const unsigned long long* __restrict__ ovf,
        const float* __restrict__ weight, const float* __restrict__ bias,
        float* __restrict__ out, int d, int n, int slots) {
    __shared__ unsigned long long stage[CC];   // 24 KB
    __shared__ int histR[DMAX], scR[DMAX];     // 1 KB
    extern __shared__ float acc[];             // d*64 floats (25 KB @ d=98)
    int b = blockIdx.x, t = threadIdx.x;
    int row0 = b * d;
    if (row0 >= n) return;
    int nrows = min(d, n - row0);
    long long sbase = (long long)b * slots;
    int cnt = cursorF[b * CSTR] - (int)sbase;
    if (cnt > slots) cnt = slots;
    if (cnt < 0) cnt = 0;

    for (int i = t; i < (nrows << 6); i += SP_T) acc[i] = 0.0f;

    int g = t >> 4, fq = t & 15;
    for (int cb = 0; cb < cnt; cb += CC) {
        int ccnt = min(CC, cnt - cb);
        if (t < DMAX) histR[t] = 0;
        __syncthreads();
        int lr6[6], rk6[6];
        unsigned long long pk6[6];
#pragma unroll
        for (int k = 0; k < 6; ++k) {
            int i = t + (k << 9);
            lr6[k] = -1;
            if (i < ccnt) {
                unsigned long long p = pairs[sbase + cb + i];
                int lr = (int)((p >> 13) & 127);
                lr6[k] = lr;
                rk6[k] = atomicAdd(&histR[lr], 1);
                pk6[k] = p;
            }
        }
        __syncthreads();
        if (t < DMAX) {
            int v = histR[t], x = v;
            int lane = t & 63;
#pragma unroll
            for (int off = 1; off < 64; off <<= 1) {
                int y = __shfl_up(x, off, 64);
                if (lane >= off) x += y;
            }
            scR[t] = x;
        }
        __syncthreads();
        if (t >= 64 && t < DMAX) scR[t] += scR[63];
        __syncthreads();
#pragma unroll
        for (int k = 0; k < 6; ++k)
            if (lr6[k] >= 0) stage[(scR[lr6[k]] - histR[lr6[k]]) + rk6[k]] = pk6[k];
        __syncthreads();

        for (int r = g; r < nrows; r += 32) {
            int e = scR[r], s = e - histR[r];
            if (s >= e) continue;
            float4 a = {0.0f, 0.0f, 0.0f, 0.0f};
            int j = s;
            for (; j + 4 <= e; j += 4) {
                unsigned long long p0 = stage[j + 0];
                unsigned long long p1 = stage[j + 1];
                unsigned long long p2 = stage[j + 2];
                unsigned long long p3 = stage[j + 3];
                const float4 w0 = *(const float4*)(weight + (((int)(p0 & 8191)) << 6) + (fq << 2));
                const float4 w1 = *(const float4*)(weight + (((int)(p1 & 8191)) << 6) + (fq << 2));
                const float4 w2 = *(const float4*)(weight + (((int)(p2 & 8191)) << 6) + (fq << 2));
                const float4 w3 = *(const float4*)(weight + (((int)(p3 & 8191)) << 6) + (fq << 2));
                float v0 = __uint_as_float((unsigned)(p0 >> 32));
                float v1 = __uint_as_float((unsigned)(p1 >> 32));
                float v2 = __uint_as_float((unsigned)(p2 >> 32));
                float v3 = __uint_as_float((unsigned)(p3 >> 32));
                a.x = fmaf(v0, w0.x, a.x); a.y = fmaf(v0, w0.y, a.y);
                a.z = fmaf(v0, w0.z, a.z); a.w = fmaf(v0, w0.w, a.w);
                a.x = fmaf(v1, w1.x, a.x); a.y = fmaf(v1, w1.y, a.y);
                a.z = fmaf(v1, w1.z, a.z); a.w = fmaf(v1, w1.w, a.w);
                a.x = fmaf(v2, w2.x, a.x); a.y = fmaf(v2, w2.y, a.y);
                a.z = fmaf(v2, w2.z, a.z); a.w = fmaf(v2, w2.w, a.w);
                a.x = fmaf(v3, w3.x, a.x); a.y = fmaf(v3, w3.y, a.y);
                a.z = fmaf(v3, w3.z, a.z); a.w = fmaf(v3, w3.w, a.w);
            }
            for (; j < e; ++j) {
                unsigned long long p = stage[j];
                float vv = __uint_as_float((unsigned)(p >> 32));
                const float4 w = *(const float4*)(weight + (((int)(p & 8191)) << 6) + (fq << 2));
                a.x = fmaf(vv, w.x, a.x); a.y = fmaf(vv, w.y, a.y);
                a.z = fmaf(vv, w.z, a.z); a.w = fmaf(vv, w.w, a.w);
            }
            float4* ap = (float4*)&acc[(r << 6) + (fq << 2)];
            float4 o = *ap;
            o.x += a.x; o.y += a.y; o.z += a.z; o.w += a.w;
            *ap = o;
        }
        __syncthreads();
    }

    // overflow (spilled pairs): statistically empty for uniform rows.
    int oc = *ovfCnt;
    if (oc > 0) {
        __syncthreads();
        for (int i = g; i < oc; i += (SP_T >> 4)) {
            unsigned long long p = ovf[i];
            if ((int)((p >> 20) & 1023) == b) {
                int lr = (int)((p >> 13) & 127);
                int cc = (int)(p & 8191);
                float vv = __uint_as_float((unsigned)(p >> 32));
                const float4 w = *(const float4*)(weight + (cc << 6) + (fq << 2));
                float* ap = &acc[(lr << 6) + (fq << 2)];
                ds_fadd(ap + 0, vv * w.x); ds_fadd(ap + 1, vv * w.y);
                ds_fadd(ap + 2, vv * w.z); ds_fadd(ap + 3, vv * w.w);
            }
        }
        asm volatile("s_waitcnt lgkmcnt(0)" ::: "memory");
        __builtin_amdgcn_sched_barrier(0);
        __syncthreads();
    }

    for (int i = t; i < (nrows << 6); i += SP_T)
        out[((long long)row0 << 6) + i] = acc[i] + bias[i & 63];
}

extern "C" void kernel_launch(void* const* d_in, const int* in_sizes, int n_in,
                              void* d_out, int out_size, void* d_ws, size_t ws_size,
                              hipStream_t stream) {
    const int*   index  = (const int*)d_in[0];
    const float* value  = (const float*)d_in[1];
    const float* weight = (const float*)d_in[3];
    const float* bias   = (const float*)d_in[4];
    float*       out    = (float*)d_out;

    int nnz = in_sizes[0] / 2;
    int n   = out_size / 64;
    const int* rows = index;
    const int* cols = index + nnz;

    int d = (n + NBF - 1) / NBF;  // 98 for n=100000 (<= DMAX)
    unsigned M = 0;
    int S = 0;
    for (S = 20; S <= 40; ++S) {
        unsigned long long m = ((1ull << S) + (unsigned)d - 1) / (unsigned)d;
        unsigned long long e = m * (unsigned long long)d - (1ull << S);
        if (m <= 0xffffffffull && e * (unsigned long long)(n > 0 ? n - 1 : 0) < (1ull << S)) {
            M = (unsigned)m;
            break;
        }
    }

    int nChunks = (nnz + CH - 1) / CH;
    char* ws = (char*)d_ws;
    int* cursorF = (int*)ws;                  // 64 KB (1024 counters, 64B stride)
    int* ovfCnt  = (int*)(ws + (64 << 10));
    unsigned long long* pairsS = (unsigned long long*)(ws + (128 << 10));

    size_t szOvf = (((size_t)nnz * 8) + 255) & ~(size_t)255;
    size_t availS = (ws_size > (128 << 10) + szOvf) ? (ws_size - (128 << 10) - szOvf) : 0;
    long long slotsL = (long long)(availS / ((size_t)NBF * 8));
    int slots = (int)(slotsL > 6144 ? 6144 : slotsL);
    if (slots > 64) slots &= ~63;
    if (slots < 1) slots = 1;
    unsigned long long* ovf = (unsigned long long*)(ws + (128 << 10) + (size_t)slots * NBF * 8);

    k_init<<<1, 1024, 0, stream>>>(cursorF, ovfCnt, slots);
    k_bin_fixed<<<nChunks, 1024, 0, stream>>>(rows, cols, value, nnz, M, S, d, slots,
                                              cursorF, pairsS, ovfCnt, ovf);
    size_t smem = (size_t)d * 64 * sizeof(float);
    k_spmm9<<<NBF, SP_T, smem, stream>>>(pairsS, cursorF, ovfCnt, ovf, weight, bias,
                                         out, d, n, slots);
}

// Round 9
// 183.839 us; speedup vs baseline: 1.0665x; 1.0041x over previous
//
#include <hip/hip_runtime.h>

// out[r,f] = bias[f] + sum_{i: rows[i]==r} value[i] * weight[cols[i], f]
// R17 pipeline (3 kernels): k_init -> k_bin_fixed (CH=8192, full-line runs,
// ~44us confirmed) -> k_spmm10 (CC=1536 / 4 blocks/CU restored + 8-wide
// batched weight loads for deeper memory-level parallelism).
// History: R9/R11: LDS atomic accumulate -> 1310us dead end. R14/R16: ANY
// LDS growth that drops consumer occupancy 4->3 blocks/CU regresses (69us
// both times) -> consume phase is TLP/latency-bound. R15: cursor padding
// null; bin's real cost was 32B-run write fragmentation, fixed by CH=8192
// (WRITE_SIZE 80->~50MB, bin 63->~44us). R17: consumer was at 66 GB/s/CU
// of L2 gather vs 135 ceiling, VALUBusy 36% -> latency-bound with only 4
// loads in flight; 8-wide batch doubles outstanding loads (VGPR ~52-58,
// still 4 blocks/CU under launch_bounds(512,8)).
//
// pair pack (u64): val[63:32] | fine[29:20] | lr[19:13] | col[12:0]

#define NBF 1024
#define DMAX 128     // lr 7 bits => d <= 128 (n <= 131072)
#define CH 8192      // binning chunk (8/thread)
#define CC 1536      // consumer sort chunk (3/thread, 4 blocks/CU)
#define SP_T 512
#define CSTR 16      // cursorF stride (ints)

__device__ __forceinline__ void ds_fadd(float* p, float v) {
    unsigned a = (unsigned)(unsigned long long)p;  // LDS byte offset
    asm volatile("ds_add_f32 %0, %1" :: "v"(a), "v"(v) : "memory");
}

__global__ void k_init(int* __restrict__ cursorF, int* __restrict__ ovfCnt, int slots) {
    cursorF[threadIdx.x * CSTR] = threadIdx.x * slots;
    if (threadIdx.x == 0) *ovfCnt = 0;
}

// Single-pass fine bin into fixed-stride bucket slots. Per-chunk LDS hist +
// scan + stage; one global atomicAdd per (block,bin) reserves space; spill
// to ovf on window overflow (statistically never for uniform rows).
__global__ __launch_bounds__(1024) void k_bin_fixed(const int* __restrict__ rows,
        const int* __restrict__ cols, const float* __restrict__ vals, int nnz,
        unsigned M, int S, int d, int slots, int* __restrict__ cursorF,
        unsigned long long* __restrict__ pairs1, int* __restrict__ ovfCnt,
        unsigned long long* __restrict__ ovf) {
    __shared__ unsigned long long stage[CH];       // 64 KB
    __shared__ int histF[NBF], scF[NBF], adjF[NBF];// 12 KB
    __shared__ int wsum[16];
    int t = threadIdx.x, lane = t & 63, wv = t >> 6;
    long long base = (long long)blockIdx.x * CH;
    int count = (int)min((long long)CH, (long long)nnz - base);
    histF[t] = 0;
    __syncthreads();
    int f8[8], rk8[8];
    unsigned long long pk8[8];
#pragma unroll
    for (int k = 0; k < 8; ++k) {
        int i = t + (k << 10);
        f8[k] = -1;
        if (i < count) {
            unsigned r = (unsigned)rows[base + i];
            int c = cols[base + i];
            float vv = vals[base + i];
            int f = (int)(((unsigned long long)r * M) >> S);
            int lr = (int)r - f * d;
            f8[k] = f;
            rk8[k] = atomicAdd(&histF[f], 1);
            pk8[k] = ((unsigned long long)__float_as_uint(vv) << 32) |
                     ((unsigned)f << 20) | ((unsigned)lr << 13) | (unsigned)c;
        }
    }
    __syncthreads();
    int v = histF[t], x = v;
#pragma unroll
    for (int off = 1; off < 64; off <<= 1) {
        int y = __shfl_up(x, off, 64);
        if (lane >= off) x += y;
    }
    if (lane == 63) wsum[wv] = x;
    __syncthreads();
    if (t < 16) {
        int s = wsum[t], xs = s;
#pragma unroll
        for (int off = 1; off < 16; off <<= 1) {
            int y = __shfl_up(xs, off, 16);
            if (t >= off) xs += y;
        }
        wsum[t] = xs - s;
    }
    __syncthreads();
    int incl = x + wsum[wv];
    scF[t] = incl;
    if (v > 0) {
        int g = atomicAdd(&cursorF[t * CSTR], v);
        adjF[t] = g - (incl - v);
    }
    __syncthreads();
#pragma unroll
    for (int k = 0; k < 8; ++k)
        if (f8[k] >= 0) stage[(scF[f8[k]] - histF[f8[k]]) + rk8[k]] = pk8[k];
    __syncthreads();
    for (int i = t; i < count; i += 1024) {
        unsigned long long p = stage[i];
        int f = (int)((p >> 20) & 1023);
        int dest = adjF[f] + i;
        if (dest < (f + 1) * slots) pairs1[dest] = p;
        else ovf[atomicAdd(ovfCnt, 1)] = p;
    }
}

// Consumer: CC=1536, 38.4 KB LDS -> 4 blocks/CU. Sort chunk by local row
// (int LDS atomics + shfl scan), then 16-lane groups walk whole rows with
// 8-wide batched weight loads (8 independent dwordx4 in flight before the
// FMA drain), 4-wide mid, scalar tail. Overflow tail via ds_add_f32 +
// explicit lgkmcnt drain (R11 lesson).
__global__ __launch_bounds__(SP_T, 8) void k_spmm10(
        const unsigned long long* __restrict__ pairs, const int* __restrict__ cursorF,
        const int* __restrict__ ovfCnt, const unsigned long long* __restrict__ ovf,
        const float* __restrict__ weight, const float* __restrict__ bias,
        float* __restrict__ out, int d, int n, int slots) {
    __shared__ unsigned long long stage[CC];   // 12 KB
    __shared__ int histR[DMAX], scR[DMAX];     // 1 KB
    extern __shared__ float acc[];             // d*64 floats (25 KB @ d=98)
    int b = blockIdx.x, t = threadIdx.x;
    int row0 = b * d;
    if (row0 >= n) return;
    int nrows = min(d, n - row0);
    long long sbase = (long long)b * slots;
    int cnt = cursorF[b * CSTR] - (int)sbase;
    if (cnt > slots) cnt = slots;
    if (cnt < 0) cnt = 0;

    for (int i = t; i < (nrows << 6); i += SP_T) acc[i] = 0.0f;

    int g = t >> 4, fq = t & 15;
    const float* wbase = weight + (fq << 2);
    for (int cb = 0; cb < cnt; cb += CC) {
        int ccnt = min(CC, cnt - cb);
        if (t < DMAX) histR[t] = 0;
        __syncthreads();
        int lr3[3], rk3[3];
        unsigned long long pk3[3];
#pragma unroll
        for (int k = 0; k < 3; ++k) {
            int i = t + (k << 9);
            lr3[k] = -1;
            if (i < ccnt) {
                unsigned long long p = pairs[sbase + cb + i];
                int lr = (int)((p >> 13) & 127);
                lr3[k] = lr;
                rk3[k] = atomicAdd(&histR[lr], 1);
                pk3[k] = p;
            }
        }
        __syncthreads();
        if (t < DMAX) {
            int v = histR[t], x = v;
            int lane = t & 63;
#pragma unroll
            for (int off = 1; off < 64; off <<= 1) {
                int y = __shfl_up(x, off, 64);
                if (lane >= off) x += y;
            }
            scR[t] = x;
        }
        __syncthreads();
        if (t >= 64 && t < DMAX) scR[t] += scR[63];
        __syncthreads();
#pragma unroll
        for (int k = 0; k < 3; ++k)
            if (lr3[k] >= 0) stage[(scR[lr3[k]] - histR[lr3[k]]) + rk3[k]] = pk3[k];
        __syncthreads();

        for (int r = g; r < nrows; r += 32) {
            int e = scR[r], s = e - histR[r];
            if (s >= e) continue;
            float4 a = {0.0f, 0.0f, 0.0f, 0.0f};
            int j = s;
            for (; j + 8 <= e; j += 8) {
                int c0, c1, c2, c3, c4, c5, c6, c7;
                float v0, v1, v2, v3, v4, v5, v6, v7;
                {
                    unsigned long long q0 = stage[j + 0], q1 = stage[j + 1];
                    unsigned long long q2 = stage[j + 2], q3 = stage[j + 3];
                    unsigned long long q4 = stage[j + 4], q5 = stage[j + 5];
                    unsigned long long q6 = stage[j + 6], q7 = stage[j + 7];
                    c0 = (int)(q0 & 8191); v0 = __uint_as_float((unsigned)(q0 >> 32));
                    c1 = (int)(q1 & 8191); v1 = __uint_as_float((unsigned)(q1 >> 32));
                    c2 = (int)(q2 & 8191); v2 = __uint_as_float((unsigned)(q2 >> 32));
                    c3 = (int)(q3 & 8191); v3 = __uint_as_float((unsigned)(q3 >> 32));
                    c4 = (int)(q4 & 8191); v4 = __uint_as_float((unsigned)(q4 >> 32));
                    c5 = (int)(q5 & 8191); v5 = __uint_as_float((unsigned)(q5 >> 32));
                    c6 = (int)(q6 & 8191); v6 = __uint_as_float((unsigned)(q6 >> 32));
                    c7 = (int)(q7 & 8191); v7 = __uint_as_float((unsigned)(q7 >> 32));
                }
                const float4 w0 = *(const float4*)(wbase + (c0 << 6));
                const float4 w1 = *(const float4*)(wbase + (c1 << 6));
                const float4 w2 = *(const float4*)(wbase + (c2 << 6));
                const float4 w3 = *(const float4*)(wbase + (c3 << 6));
                const float4 w4 = *(const float4*)(wbase + (c4 << 6));
                const float4 w5 = *(const float4*)(wbase + (c5 << 6));
                const float4 w6 = *(const float4*)(wbase + (c6 << 6));
                const float4 w7 = *(const float4*)(wbase + (c7 << 6));
                a.x = fmaf(v0, w0.x, a.x); a.y = fmaf(v0, w0.y, a.y);
                a.z = fmaf(v0, w0.z, a.z); a.w = fmaf(v0, w0.w, a.w);
                a.x = fmaf(v1, w1.x, a.x); a.y = fmaf(v1, w1.y, a.y);
                a.z = fmaf(v1, w1.z, a.z); a.w = fmaf(v1, w1.w, a.w);
                a.x = fmaf(v2, w2.x, a.x); a.y = fmaf(v2, w2.y, a.y);
                a.z = fmaf(v2, w2.z, a.z); a.w = fmaf(v2, w2.w, a.w);
                a.x = fmaf(v3, w3.x, a.x); a.y = fmaf(v3, w3.y, a.y);
                a.z = fmaf(v3, w3.z, a.z); a.w = fmaf(v3, w3.w, a.w);
                a.x = fmaf(v4, w4.x, a.x); a.y = fmaf(v4, w4.y, a.y);
                a.z = fmaf(v4, w4.z, a.z); a.w = fmaf(v4, w4.w, a.w);
                a.x = fmaf(v5, w5.x, a.x); a.y = fmaf(v5, w5.y, a.y);
                a.z = fmaf(v5, w5.z, a.z); a.w = fmaf(v5, w5.w, a.w);
                a.x = fmaf(v6, w6.x, a.x); a.y = fmaf(v6, w6.y, a.y);
                a.z = fmaf(v6, w6.z, a.z); a.w = fmaf(v6, w6.w, a.w);
                a.x = fmaf(v7, w7.x, a.x); a.y = fmaf(v7, w7.y, a.y);
                a.z = fmaf(v7, w7.z, a.z); a.w = fmaf(v7, w7.w, a.w);
            }
            for (; j + 4 <= e; j += 4) {
                unsigned long long q0 = stage[j + 0], q1 = stage[j + 1];
                unsigned long long q2 = stage[j + 2], q3 = stage[j + 3];
                const float4 w0 = *(const float4*)(wbase + ((int)(q0 & 8191) << 6));
                const float4 w1 = *(const float4*)(wbase + ((int)(q1 & 8191) << 6));
                const float4 w2 = *(const float4*)(wbase + ((int)(q2 & 8191) << 6));
                const float4 w3 = *(const float4*)(wbase + ((int)(q3 & 8191) << 6));
                float v0 = __uint_as_float((unsigned)(q0 >> 32));
                float v1 = __uint_as_float((unsigned)(q1 >> 32));
                float v2 = __uint_as_float((unsigned)(q2 >> 32));
                float v3 = __uint_as_float((unsigned)(q3 >> 32));
                a.x = fmaf(v0, w0.x, a.x); a.y = fmaf(v0, w0.y, a.y);
                a.z = fmaf(v0, w0.z, a.z); a.w = fmaf(v0, w0.w, a.w);
                a.x = fmaf(v1, w1.x, a.x); a.y = fmaf(v1, w1.y, a.y);
                a.z = fmaf(v1, w1.z, a.z); a.w = fmaf(v1, w1.w, a.w);
                a.x = fmaf(v2, w2.x, a.x); a.y = fmaf(v2, w2.y, a.y);
                a.z = fmaf(v2, w2.z, a.z); a.w = fmaf(v2, w2.w, a.w);
                a.x = fmaf(v3, w3.x, a.x); a.y = fmaf(v3, w3.y, a.y);
                a.z = fmaf(v3, w3.z, a.z); a.w = fmaf(v3, w3.w, a.w);
            }
            for (; j < e; ++j) {
                unsigned long long p = stage[j];
                float vv = __uint_as_float((unsigned)(p >> 32));
                const float4 w = *(const float4*)(wbase + ((int)(p & 8191) << 6));
                a.x = fmaf(vv, w.x, a.x); a.y = fmaf(vv, w.y, a.y);
                a.z = fmaf(vv, w.z, a.z); a.w = fmaf(vv, w.w, a.w);
            }
            float4* ap = (float4*)&acc[(r << 6) + (fq << 2)];
            float4 o = *ap;
            o.x += a.x; o.y += a.y; o.z += a.z; o.w += a.w;
            *ap = o;
        }
        __syncthreads();
    }

    // overflow (spilled pairs): statistically empty for uniform rows.
    int oc = *ovfCnt;
    if (oc > 0) {
        __syncthreads();
        for (int i = g; i < oc; i += (SP_T >> 4)) {
            unsigned long long p = ovf[i];
            if ((int)((p >> 20) & 1023) == b) {
                int lr = (int)((p >> 13) & 127);
                int cc = (int)(p & 8191);
                float vv = __uint_as_float((unsigned)(p >> 32));
                const float4 w = *(const float4*)(weight + (cc << 6) + (fq << 2));
                float* ap = &acc[(lr << 6) + (fq << 2)];
                ds_fadd(ap + 0, vv * w.x); ds_fadd(ap + 1, vv * w.y);
                ds_fadd(ap + 2, vv * w.z); ds_fadd(ap + 3, vv * w.w);
            }
        }
        asm volatile("s_waitcnt lgkmcnt(0)" ::: "memory");
        __builtin_amdgcn_sched_barrier(0);
        __syncthreads();
    }

    for (int i = t; i < (nrows << 6); i += SP_T)
        out[((long long)row0 << 6) + i] = acc[i] + bias[i & 63];
}

extern "C" void kernel_launch(void* const* d_in, const int* in_sizes, int n_in,
                              void* d_out, int out_size, void* d_ws, size_t ws_size,
                              hipStream_t stream) {
    const int*   index  = (const int*)d_in[0];
    const float* value  = (const float*)d_in[1];
    const float* weight = (const float*)d_in[3];
    const float* bias   = (const float*)d_in[4];
    float*       out    = (float*)d_out;

    int nnz = in_sizes[0] / 2;
    int n   = out_size / 64;
    const int* rows = index;
    const int* cols = index + nnz;

    int d = (n + NBF - 1) / NBF;  // 98 for n=100000 (<= DMAX)
    unsigned M = 0;
    int S = 0;
    for (S = 20; S <= 40; ++S) {
        unsigned long long m = ((1ull << S) + (unsigned)d - 1) / (unsigned)d;
        unsigned long long e = m * (unsigned long long)d - (1ull << S);
        if (m <= 0xffffffffull && e * (unsigned long long)(n > 0 ? n - 1 : 0) < (1ull << S)) {
            M = (unsigned)m;
            break;
        }
    }

    int nChunks = (nnz + CH - 1) / CH;
    char* ws = (char*)d_ws;
    int* cursorF = (int*)ws;                  // 64 KB (1024 counters, 64B stride)
    int* ovfCnt  = (int*)(ws + (64 << 10));
    unsigned long long* pairsS = (unsigned long long*)(ws + (128 << 10));

    size_t szOvf = (((size_t)nnz * 8) + 255) & ~(size_t)255;
    size_t availS = (ws_size > (128 << 10) + szOvf) ? (ws_size - (128 << 10) - szOvf) : 0;
    long long slotsL = (long long)(availS / ((size_t)NBF * 8));
    int slots = (int)(slotsL > 6144 ? 6144 : slotsL);
    if (slots > 64) slots &= ~63;
    if (slots < 1) slots = 1;
    unsigned long long* ovf = (unsigned long long*)(ws + (128 << 10) + (size_t)slots * NBF * 8);

    k_init<<<1, 1024, 0, stream>>>(cursorF, ovfCnt, slots);
    k_bin_fixed<<<nChunks, 1024, 0, stream>>>(rows, cols, value, nnz, M, S, d, slots,
                                              cursorF, pairsS, ovfCnt, ovf);
    size_t smem = (size_t)d * 64 * sizeof(float);
    k_spmm10<<<NBF, SP_T, smem, stream>>>(pairsS, cursorF, ovfCnt, ovf, weight, bias,
                                          out, d, n, slots);
}